// Round 4
// baseline (296.281 us; speedup 1.0000x reference)
//
#include <hip/hip_runtime.h>
#include <cstdint>
#include <cstddef>

typedef __attribute__((ext_vector_type(8))) short s16x8;   // 8 x bf16 bits
typedef __attribute__((ext_vector_type(4))) float fx4;     // MFMA accumulator

#define AS1 __attribute__((address_space(1)))
#define AS3 __attribute__((address_space(3)))

__device__ __forceinline__ unsigned short f2bf(float f) {
    union { float f; unsigned u; } c; c.f = f;
    unsigned lsb = (c.u >> 16) & 1u;
    unsigned r = c.u + 0x7fffu + lsb;
    return (unsigned short)(r >> 16);
}

// ---------------- conversion kernels ----------------
__global__ __launch_bounds__(256) void conv4(const float* __restrict__ src,
                                             unsigned short* __restrict__ dst, int n4) {
    int i = blockIdx.x * 256 + threadIdx.x;
    if (i >= n4) return;
    float4 v = reinterpret_cast<const float4*>(src)[i];
    ushort4 o;
    o.x = f2bf(v.x); o.y = f2bf(v.y); o.z = f2bf(v.z); o.w = f2bf(v.w);
    reinterpret_cast<ushort4*>(dst)[i] = o;
}

// W [Kfull x N] fp32 -> WT [N x K] bf16 (first K rows only)
__global__ __launch_bounds__(256) void convT(const float* __restrict__ W,
                                             unsigned short* __restrict__ WT, int K, int N) {
    int i = blockIdx.x * 256 + threadIdx.x;
    if (i >= N * K) return;
    int n = i / K, k = i - n * K;
    WT[i] = f2bf(W[(size_t)k * N + n]);
}

// bias fold: bout[n] = b1[n] + sum_k g[k] * W1[(K0+k)*N + n]   (fp32 exact)
__global__ __launch_bounds__(256) void foldbias(const float* __restrict__ g,
                                                const float* __restrict__ W1,
                                                const float* __restrict__ b1,
                                                float* __restrict__ bout,
                                                int K0, int N) {
    int n = blockIdx.x * 256 + threadIdx.x;
    if (n >= N) return;
    float s = b1[n];
    for (int k = 0; k < 256; ++k) s += g[k] * W1[(size_t)(K0 + k) * N + n];
    bout[n] = s;
}

// ---------------- m201-style 8-phase 256x256 fused GEMM ----------------
// C = ReLU(A @ W + bias), A gathered (MODE 1/2) or dense (MODE 0).
// BM=256, BN=256, BK=64; 8 waves = 2(M) x 4(N), wave tile 128x64.
// LDS: 2 buffers x (A 32KB | B 32KB) = 128KB (+4KB reduce scratch).
// 2 K-tiles per iteration, 8 phases; stage schedule as before; vmcnt(2) at ph4/ph8.
// Global-embedding segment is folded into bias on host side (K excludes it).
// FOUT: fuse final 256->1 dot (Wc2, bc2) into the epilogue, write fp32 out.
template <int MODE, int K, int NODES, bool FOUT>
__global__ __launch_bounds__(512, 2) void gemm256(
    const unsigned short* __restrict__ Abase,
    const int* __restrict__ idx,
    const unsigned short* __restrict__ WT,
    const float* __restrict__ bias,
    unsigned short* __restrict__ Hout,
    float* __restrict__ outF,
    const float* __restrict__ Wc2,
    const float* __restrict__ bc2,
    int N, int nbn) {
    __shared__ alignas(16) char smem_c[131072 + 4096];
    constexpr int KT = K / 64;

    const int t = threadIdx.x;
    const int w = t >> 6, lane = t & 63;
    const int wm = w >> 2, wn = w & 3;  // 2M x 4N waves

    // XCD-chunked bijective swizzle (grid % 8 == 0 in all launches), bn-fastest
    const int nwg = gridDim.x, o = blockIdx.x, q = nwg >> 3;
    const int widx = (o & 7) * q + (o >> 3);
    const int bn = widx % nbn, bm = widx / nbn;

    // staging geometry: granule r of wave w -> LDS rows w*8 + (lane>>3) + r*64
    const int l3 = lane >> 3, l7 = lane & 7, l15 = lane & 15;
    const int scs = (l7 ^ l3) << 4;  // pre-swizzled source col (involution)

    const char* Abc = (const char*)Abase;
    const char* WTc = (const char*)WT;

    uint32_t boff[2][2];
    uint32_t aoff[2][2][NODES];
#pragma unroll
    for (int h = 0; h < 2; ++h)
#pragma unroll
        for (int r = 0; r < 2; ++r) {
            int srow = h * 128 + w * 8 + l3 + r * 64;
            boff[h][r] = (uint32_t)(bn * 256 + srow) * (uint32_t)(K * 2) + scs;
            int gm = bm * 256 + srow;
            if constexpr (MODE == 0) {
                aoff[h][r][0] = (uint32_t)gm * (uint32_t)(K * 2) + scs;
            } else {
#pragma unroll
                for (int s = 0; s < NODES; ++s)
                    aoff[h][r][s] = (uint32_t)idx[(size_t)gm * NODES + s] * 512u + scs;
            }
        }

#define GLL(src, dst) __builtin_amdgcn_global_load_lds((AS1 void*)(src), (AS3 void*)(dst), 16, 0, 0)

#define STAGE_A(hh, tsrc, pb) do { \
    char* d_ = smem_c + (pb) * 65536 + (hh) * 16384 + (w << 10); \
    if constexpr (MODE == 0) { \
        GLL(Abc + aoff[hh][0][0] + (tsrc) * 128, d_); \
        GLL(Abc + aoff[hh][1][0] + (tsrc) * 128, d_ + 8192); \
    } else { \
        int seg_ = (tsrc) >> 2, k4_ = ((tsrc) & 3) << 7; \
        uint32_t v0_ = aoff[hh][0][0], v1_ = aoff[hh][1][0]; \
        if constexpr (NODES >= 2) { if (seg_ >= 1) { v0_ = aoff[hh][0][1]; v1_ = aoff[hh][1][1]; } } \
        if constexpr (NODES >= 3) { if (seg_ >= 2) { v0_ = aoff[hh][0][2]; v1_ = aoff[hh][1][2]; } } \
        GLL(Abc + v0_ + k4_, d_); GLL(Abc + v1_ + k4_, d_ + 8192); \
    } \
} while (0)

#define STAGE_B(hh, tsrc, pb) do { \
    char* d_ = smem_c + (pb) * 65536 + 32768 + (hh) * 16384 + (w << 10); \
    GLL(WTc + boff[hh][0] + (tsrc) * 128, d_); \
    GLL(WTc + boff[hh][1] + (tsrc) * 128, d_ + 8192); \
} while (0)

    // fragment-read geometry
    const int armul = wm * 16384 + l15 * 128;          // A: row base (within buf)
    const int brmul = 32768 + wn * 8192 + l15 * 128;   // B: row base (within buf)
    const int hi = (lane >> 4) << 4, xl = l7 << 4;
    const int c0 = hi ^ xl, c1 = (64 + hi) ^ xl;

#define READ_A(mh, pb) do { \
    const char* base_ = smem_c + (pb) * 65536 + armul; \
    _Pragma("unroll") for (int r_ = 0; r_ < 4; ++r_) { \
        a[r_ * 2 + 0] = *(const s16x8*)(base_ + ((mh) * 4 + r_) * 2048 + c0); \
        a[r_ * 2 + 1] = *(const s16x8*)(base_ + ((mh) * 4 + r_) * 2048 + c1); \
    } \
} while (0)

#define READ_B(nh, pb, BARR) do { \
    const char* base_ = smem_c + (pb) * 65536 + brmul; \
    _Pragma("unroll") for (int c_ = 0; c_ < 2; ++c_) { \
        BARR[c_ * 2 + 0] = *(const s16x8*)(base_ + ((nh) * 2 + c_) * 2048 + c0); \
        BARR[c_ * 2 + 1] = *(const s16x8*)(base_ + ((nh) * 2 + c_) * 2048 + c1); \
    } \
} while (0)

#define MFMA16(mh, nh, BARR) do { \
    _Pragma("unroll") for (int ks_ = 0; ks_ < 2; ++ks_) \
    _Pragma("unroll") for (int r_ = 0; r_ < 4; ++r_) \
    _Pragma("unroll") for (int c_ = 0; c_ < 2; ++c_) \
        acc[(mh) * 4 + r_][(nh) * 2 + c_] = __builtin_amdgcn_mfma_f32_16x16x32_bf16( \
            a[r_ * 2 + ks_], BARR[c_ * 2 + ks_], acc[(mh) * 4 + r_][(nh) * 2 + c_], 0, 0, 0); \
} while (0)

#define SYNC_PRE() do { \
    __builtin_amdgcn_s_barrier(); \
    asm volatile("s_waitcnt lgkmcnt(0)" ::: "memory"); \
    __builtin_amdgcn_sched_barrier(0); \
    __builtin_amdgcn_s_setprio(1); \
} while (0)

    fx4 acc[8][4];
#pragma unroll
    for (int i = 0; i < 8; ++i)
#pragma unroll
        for (int j = 0; j < 4; ++j) acc[i][j] = {0.f, 0.f, 0.f, 0.f};

    // ---- prologue: tile 0 full + tile 1 A0 ----
    STAGE_A(0, 0, 0); STAGE_A(1, 0, 0); STAGE_B(0, 0, 0); STAGE_B(1, 0, 0);
    STAGE_A(0, 1, 1);
    asm volatile("s_waitcnt vmcnt(2)" ::: "memory");
    __builtin_amdgcn_s_barrier();

    s16x8 a[8], bl[4], bh[4];
    for (int tt = 0; tt < KT; tt += 2) {
        const int t1 = tt + 1;
        const int t2c = (tt + 2 < KT) ? tt + 2 : KT - 1;
        const int t3c = (tt + 3 < KT) ? tt + 3 : KT - 1;

        // ---- tile tt (buf0) ----
        READ_A(0, 0); READ_B(0, 0, bl);
        STAGE_A(1, t1, 1);
        SYNC_PRE(); MFMA16(0, 0, bl); __builtin_amdgcn_s_setprio(0);
        __builtin_amdgcn_s_barrier();

        READ_B(1, 0, bh);
        STAGE_B(0, t1, 1);
        SYNC_PRE(); MFMA16(0, 1, bh); __builtin_amdgcn_s_setprio(0);
        __builtin_amdgcn_s_barrier();

        READ_A(1, 0);
        STAGE_B(1, t1, 1);
        SYNC_PRE(); MFMA16(1, 0, bl); __builtin_amdgcn_s_setprio(0);
        __builtin_amdgcn_s_barrier();

        STAGE_A(0, t2c, 0);
        SYNC_PRE(); MFMA16(1, 1, bh); __builtin_amdgcn_s_setprio(0);
        asm volatile("s_waitcnt vmcnt(2)" ::: "memory");
        __builtin_amdgcn_s_barrier();

        // ---- tile tt+1 (buf1) ----
        READ_A(0, 1); READ_B(0, 1, bl);
        STAGE_A(1, t2c, 0);
        SYNC_PRE(); MFMA16(0, 0, bl); __builtin_amdgcn_s_setprio(0);
        __builtin_amdgcn_s_barrier();

        READ_B(1, 1, bh);
        STAGE_B(0, t2c, 0);
        SYNC_PRE(); MFMA16(0, 1, bh); __builtin_amdgcn_s_setprio(0);
        __builtin_amdgcn_s_barrier();

        READ_A(1, 1);
        STAGE_B(1, t2c, 0);
        SYNC_PRE(); MFMA16(1, 0, bl); __builtin_amdgcn_s_setprio(0);
        __builtin_amdgcn_s_barrier();

        STAGE_A(0, t3c, 1);
        SYNC_PRE(); MFMA16(1, 1, bh); __builtin_amdgcn_s_setprio(0);
        asm volatile("s_waitcnt vmcnt(2)" ::: "memory");
        __builtin_amdgcn_s_barrier();
    }
    asm volatile("s_waitcnt vmcnt(0)" ::: "memory");

#undef GLL
#undef STAGE_A
#undef STAGE_B
#undef READ_A
#undef READ_B
#undef MFMA16
#undef SYNC_PRE

    const int hi2 = (lane >> 4);  // 0..3

    if constexpr (FOUT) {
        // fused: out[row] = sum_c relu(h[row][c] + bias[c]) * Wc2[c] + bc2
        float* part = (float*)(smem_c + 131072);
        float bv[4], wv[4];
#pragma unroll
        for (int ni = 0; ni < 4; ++ni) {
            int gcol = wn * 64 + ni * 16 + l15;
            bv[ni] = bias[gcol];
            wv[ni] = Wc2[gcol];
        }
#pragma unroll
        for (int mi = 0; mi < 8; ++mi) {
#pragma unroll
            for (int j = 0; j < 4; ++j) {
                float s = 0.f;
#pragma unroll
                for (int ni = 0; ni < 4; ++ni)
                    s += fmaxf(acc[mi][ni][j] + bv[ni], 0.f) * wv[ni];
                s += __shfl_xor(s, 1); s += __shfl_xor(s, 2);
                s += __shfl_xor(s, 4); s += __shfl_xor(s, 8);
                if (l15 == 0) {
                    int row = wm * 128 + mi * 16 + hi2 * 4 + j;
                    part[row * 4 + wn] = s;
                }
            }
        }
        __syncthreads();
        if (t < 256) {
            float o2 = part[t * 4] + part[t * 4 + 1] + part[t * 4 + 2] + part[t * 4 + 3] + bc2[0];
            outF[bm * 256 + t] = o2;
        }
    } else {
#pragma unroll
        for (int mi = 0; mi < 8; ++mi) {
#pragma unroll
            for (int ni = 0; ni < 4; ++ni) {
                int gcol = bn * 256 + wn * 64 + ni * 16 + l15;
                float bvv = bias[gcol];
                int grow0 = bm * 256 + wm * 128 + mi * 16 + hi2 * 4;
                fx4 v = acc[mi][ni];
#pragma unroll
                for (int j = 0; j < 4; ++j) {
                    float x = fmaxf(v[j] + bvv, 0.f);
                    Hout[(size_t)(grow0 + j) * N + gcol] = f2bf(x);
                }
            }
        }
    }
}

// ---------------- launch ----------------
extern "C" void kernel_launch(void* const* d_in, const int* in_sizes, int n_in,
                              void* d_out, int out_size, void* d_ws, size_t ws_size,
                              hipStream_t stream) {
    const float* local_emb  = (const float*)d_in[0];
    const float* global_emb = (const float*)d_in[1];
    const int* unary_idx    = (const int*)d_in[2];
    const int* binary_idx   = (const int*)d_in[3];
    const float* Wb1 = (const float*)d_in[4];
    const float* bb1 = (const float*)d_in[5];
    const float* Wb2 = (const float*)d_in[6];
    const float* bb2 = (const float*)d_in[7];
    const float* Wt1 = (const float*)d_in[8];
    const float* bt1 = (const float*)d_in[9];
    const float* Wt2 = (const float*)d_in[10];
    const float* bt2 = (const float*)d_in[11];
    const float* Wc1 = (const float*)d_in[12];
    const float* bc1 = (const float*)d_in[13];
    const float* Wc2 = (const float*)d_in[14];
    const float* bc2 = (const float*)d_in[15];
    float* out = (float*)d_out;

    constexpr int Hd = 256, U = 65536, B = 65536;
    const int NN = in_sizes[0] / Hd;

    char* ws = (char*)d_ws;
    size_t off = 0;
    auto alloc = [&](size_t bytes) {
        char* p = ws + off;
        off += (bytes + 255) & ~(size_t)255;
        return p;
    };
    unsigned short* emb_bf = (unsigned short*)alloc((size_t)NN * Hd * 2);
    unsigned short* W1uT   = (unsigned short*)alloc(512 * 512 * 2);   // first 512 rows of Wb1, T
    unsigned short* W2uT   = (unsigned short*)alloc(256 * 512 * 2);
    unsigned short* W1bT   = (unsigned short*)alloc(512 * 768 * 2);   // first 768 rows of Wt1, T
    unsigned short* W2bT   = (unsigned short*)alloc(256 * 512 * 2);
    unsigned short* Wc1T   = (unsigned short*)alloc(256 * 256 * 2);
    float* bu              = (float*)alloc(512 * 4);  // bb1 + Wb1_g @ g
    float* bbn             = (float*)alloc(512 * 4);  // bt1 + Wt1_g @ g
    unsigned short* h1     = (unsigned short*)alloc((size_t)U * 512 * 2);
    unsigned short* h2     = (unsigned short*)alloc((size_t)U * 256 * 2);

    int n4 = NN * Hd / 4;
    conv4<<<(n4 + 255) / 256, 256, 0, stream>>>(local_emb, emb_bf, n4);
    convT<<<(512 * 512 + 255) / 256, 256, 0, stream>>>(Wb1, W1uT, 512, 512);
    convT<<<(256 * 512 + 255) / 256, 256, 0, stream>>>(Wb2, W2uT, 512, 256);
    convT<<<(512 * 768 + 255) / 256, 256, 0, stream>>>(Wt1, W1bT, 768, 512);
    convT<<<(256 * 512 + 255) / 256, 256, 0, stream>>>(Wt2, W2bT, 512, 256);
    convT<<<(256 * 256 + 255) / 256, 256, 0, stream>>>(Wc1, Wc1T, 256, 256);
    foldbias<<<2, 256, 0, stream>>>(global_emb, Wb1, bb1, bu, 512, 512);
    foldbias<<<2, 256, 0, stream>>>(global_emb, Wt1, bt1, bbn, 768, 512);

    dim3 blk(512);
    // unary branch (K = 2H = 512 after bias-fold)
    gemm256<1, 512, 2, false><<<dim3(512), blk, 0, stream>>>(
        emb_bf, unary_idx, W1uT, bu, h1, nullptr, nullptr, nullptr, 512, 2);
    gemm256<0, 512, 1, false><<<dim3(256), blk, 0, stream>>>(
        h1, nullptr, W2uT, bb2, h2, nullptr, nullptr, nullptr, 256, 1);
    gemm256<0, 256, 1, true><<<dim3(256), blk, 0, stream>>>(
        h2, nullptr, Wc1T, bc1, nullptr, out, Wc2, bc2, 256, 1);
    // binary branch (K = 3H = 768 after bias-fold; reuses h1/h2)
    gemm256<2, 768, 3, false><<<dim3(512), blk, 0, stream>>>(
        emb_bf, binary_idx, W1bT, bbn, h1, nullptr, nullptr, nullptr, 512, 2);
    gemm256<0, 512, 1, false><<<dim3(256), blk, 0, stream>>>(
        h1, nullptr, W2bT, bt2, h2, nullptr, nullptr, nullptr, 256, 1);
    gemm256<0, 256, 1, true><<<dim3(256), blk, 0, stream>>>(
        h2, nullptr, Wc1T, bc1, nullptr, out + U, Wc2, bc2, 256, 1);

    (void)n_in; (void)out_size; (void)ws_size;
}

// Round 5
// 232.705 us; speedup vs baseline: 1.2732x; 1.2732x over previous
//
#include <hip/hip_runtime.h>
#include <cstdint>
#include <cstddef>

typedef __attribute__((ext_vector_type(8))) short s16x8;   // 8 x bf16 bits
typedef __attribute__((ext_vector_type(4))) float fx4;     // MFMA accumulator

#define AS1 __attribute__((address_space(1)))
#define AS3 __attribute__((address_space(3)))

__device__ __forceinline__ unsigned short f2bf(float f) {
    union { float f; unsigned u; } c; c.f = f;
    unsigned lsb = (c.u >> 16) & 1u;
    unsigned r = c.u + 0x7fffu + lsb;
    return (unsigned short)(r >> 16);
}

// ---------------- conversion kernels ----------------
__global__ __launch_bounds__(256) void conv4(const float* __restrict__ src,
                                             unsigned short* __restrict__ dst, int n4) {
    int i = blockIdx.x * 256 + threadIdx.x;
    if (i >= n4) return;
    float4 v = reinterpret_cast<const float4*>(src)[i];
    ushort4 o;
    o.x = f2bf(v.x); o.y = f2bf(v.y); o.z = f2bf(v.z); o.w = f2bf(v.w);
    reinterpret_cast<ushort4*>(dst)[i] = o;
}

// W [Kfull x N] fp32 -> WT [N x K] bf16 (first K rows only)
__global__ __launch_bounds__(256) void convT(const float* __restrict__ W,
                                             unsigned short* __restrict__ WT, int K, int N) {
    int i = blockIdx.x * 256 + threadIdx.x;
    if (i >= N * K) return;
    int n = i / K, k = i - n * K;
    WT[i] = f2bf(W[(size_t)k * N + n]);
}

// bias fold: bout[n] = b1[n] + sum_k g[k]*W1[(K0+k)*N+n]  (fp32 exact)
// one wave per n: 4 independent loads/lane, shfl reduce. grid = N.
__global__ __launch_bounds__(64) void foldbias(const float* __restrict__ g,
                                               const float* __restrict__ W1,
                                               const float* __restrict__ b1,
                                               float* __restrict__ bout,
                                               int K0, int N) {
    int n = blockIdx.x;
    int lane = threadIdx.x;
    float s = 0.f;
#pragma unroll
    for (int j = 0; j < 4; ++j) {
        int k = lane + j * 64;
        s += g[k] * W1[(size_t)(K0 + k) * N + n];
    }
#pragma unroll
    for (int off = 32; off > 0; off >>= 1) s += __shfl_xor(s, off, 64);
    if (lane == 0) bout[n] = b1[n] + s;
}

// ================= shared GEMM building-block macros =================
// BM=256, BN=256, BK=64; 8 waves = 2(M) x 4(N), wave tile 128x64.
// LDS buf layout (64KB/buf): A 32KB (2 halves of 128 rows x 128B) | B 32KB.
// Swizzle: element k of row r stored at byte (2k) ^ ((r&7)<<4) within row.

#define GLL(src, dst) __builtin_amdgcn_global_load_lds((AS1 void*)(src), (AS3 void*)(dst), 16, 0, 0)

#define MFMA16(mh, nh, BARR) do { \
    _Pragma("unroll") for (int ks_ = 0; ks_ < 2; ++ks_) \
    _Pragma("unroll") for (int r_ = 0; r_ < 4; ++r_) \
    _Pragma("unroll") for (int c_ = 0; c_ < 2; ++c_) \
        acc[(mh) * 4 + r_][(nh) * 2 + c_] = __builtin_amdgcn_mfma_f32_16x16x32_bf16( \
            a[r_ * 2 + ks_], BARR[c_ * 2 + ks_], acc[(mh) * 4 + r_][(nh) * 2 + c_], 0, 0, 0); \
} while (0)

#define SYNC_PRE() do { \
    __builtin_amdgcn_s_barrier(); \
    asm volatile("s_waitcnt lgkmcnt(0)" ::: "memory"); \
    __builtin_amdgcn_sched_barrier(0); \
    __builtin_amdgcn_s_setprio(1); \
} while (0)

#define READ_A_AT(basep, mh) do { \
    const char* base_ = (basep); \
    _Pragma("unroll") for (int r_ = 0; r_ < 4; ++r_) { \
        a[r_ * 2 + 0] = *(const s16x8*)(base_ + ((mh) * 4 + r_) * 2048 + c0); \
        a[r_ * 2 + 1] = *(const s16x8*)(base_ + ((mh) * 4 + r_) * 2048 + c1); \
    } \
} while (0)

#define READ_B_AT(basep, nh, BARR) do { \
    const char* base_ = (basep); \
    _Pragma("unroll") for (int c_ = 0; c_ < 2; ++c_) { \
        BARR[c_ * 2 + 0] = *(const s16x8*)(base_ + ((nh) * 2 + c_) * 2048 + c0); \
        BARR[c_ * 2 + 1] = *(const s16x8*)(base_ + ((nh) * 2 + c_) * 2048 + c1); \
    } \
} while (0)

// ---------------- layer-1: 8-phase 256x256 gathered GEMM ----------------
// C = ReLU(A @ W + bias) -> bf16. A gathered (MODE 1/2) or dense (MODE 0).
// Global-embedding segment folded into bias host-side (K excludes it).
template <int MODE, int K, int NODES>
__global__ __launch_bounds__(512, 2) void gemm256(
    const unsigned short* __restrict__ Abase,
    const int* __restrict__ idx,
    const unsigned short* __restrict__ WT,
    const float* __restrict__ bias,
    unsigned short* __restrict__ Hout,
    int N, int nbn) {
    __shared__ alignas(16) char smem_c[131072];
    constexpr int KT = K / 64;

    const int t = threadIdx.x;
    const int w = t >> 6, lane = t & 63;
    const int wm = w >> 2, wn = w & 3;

    const int nwg = gridDim.x, o = blockIdx.x, q = nwg >> 3;
    const int widx = (o & 7) * q + (o >> 3);
    const int bn = widx % nbn, bm = widx / nbn;

    const int l3 = lane >> 3, l7 = lane & 7, l15 = lane & 15;
    const int scs = (l7 ^ l3) << 4;

    const char* Abc = (const char*)Abase;
    const char* WTc = (const char*)WT;

    uint32_t boff[2][2];
    uint32_t aoff[2][2][NODES];
#pragma unroll
    for (int h = 0; h < 2; ++h)
#pragma unroll
        for (int r = 0; r < 2; ++r) {
            int srow = h * 128 + w * 8 + l3 + r * 64;
            boff[h][r] = (uint32_t)(bn * 256 + srow) * (uint32_t)(K * 2) + scs;
            int gm = bm * 256 + srow;
            if constexpr (MODE == 0) {
                aoff[h][r][0] = (uint32_t)gm * (uint32_t)(K * 2) + scs;
            } else {
#pragma unroll
                for (int s = 0; s < NODES; ++s)
                    aoff[h][r][s] = (uint32_t)idx[(size_t)gm * NODES + s] * 512u + scs;
            }
        }

#define STAGE_A(hh, tsrc, pb) do { \
    char* d_ = smem_c + (pb) * 65536 + (hh) * 16384 + (w << 10); \
    if constexpr (MODE == 0) { \
        GLL(Abc + aoff[hh][0][0] + (tsrc) * 128, d_); \
        GLL(Abc + aoff[hh][1][0] + (tsrc) * 128, d_ + 8192); \
    } else { \
        int seg_ = (tsrc) >> 2, k4_ = ((tsrc) & 3) << 7; \
        uint32_t v0_ = aoff[hh][0][0], v1_ = aoff[hh][1][0]; \
        if constexpr (NODES >= 2) { if (seg_ >= 1) { v0_ = aoff[hh][0][1]; v1_ = aoff[hh][1][1]; } } \
        if constexpr (NODES >= 3) { if (seg_ >= 2) { v0_ = aoff[hh][0][2]; v1_ = aoff[hh][1][2]; } } \
        GLL(Abc + v0_ + k4_, d_); GLL(Abc + v1_ + k4_, d_ + 8192); \
    } \
} while (0)

#define STAGE_B(hh, tsrc, pb) do { \
    char* d_ = smem_c + (pb) * 65536 + 32768 + (hh) * 16384 + (w << 10); \
    GLL(WTc + boff[hh][0] + (tsrc) * 128, d_); \
    GLL(WTc + boff[hh][1] + (tsrc) * 128, d_ + 8192); \
} while (0)

    const int armul = wm * 16384 + l15 * 128;
    const int brmul = 32768 + wn * 8192 + l15 * 128;
    const int hi = (lane >> 4) << 4, xl = l7 << 4;
    const int c0 = hi ^ xl, c1 = (64 + hi) ^ xl;

    fx4 acc[8][4];
#pragma unroll
    for (int i = 0; i < 8; ++i)
#pragma unroll
        for (int j = 0; j < 4; ++j) acc[i][j] = {0.f, 0.f, 0.f, 0.f};

    STAGE_A(0, 0, 0); STAGE_A(1, 0, 0); STAGE_B(0, 0, 0); STAGE_B(1, 0, 0);
    STAGE_A(0, 1, 1);
    asm volatile("s_waitcnt vmcnt(2)" ::: "memory");
    __builtin_amdgcn_s_barrier();

    s16x8 a[8], bl[4], bh[4];
    for (int tt = 0; tt < KT; tt += 2) {
        const int t1 = tt + 1;
        const int t2c = (tt + 2 < KT) ? tt + 2 : KT - 1;
        const int t3c = (tt + 3 < KT) ? tt + 3 : KT - 1;

        READ_A_AT(smem_c + armul, 0); READ_B_AT(smem_c + brmul, 0, bl);
        STAGE_A(1, t1, 1);
        SYNC_PRE(); MFMA16(0, 0, bl); __builtin_amdgcn_s_setprio(0);
        __builtin_amdgcn_s_barrier();

        READ_B_AT(smem_c + brmul, 1, bh);
        STAGE_B(0, t1, 1);
        SYNC_PRE(); MFMA16(0, 1, bh); __builtin_amdgcn_s_setprio(0);
        __builtin_amdgcn_s_barrier();

        READ_A_AT(smem_c + armul, 1);
        STAGE_B(1, t1, 1);
        SYNC_PRE(); MFMA16(1, 0, bl); __builtin_amdgcn_s_setprio(0);
        __builtin_amdgcn_s_barrier();

        STAGE_A(0, t2c, 0);
        SYNC_PRE(); MFMA16(1, 1, bh); __builtin_amdgcn_s_setprio(0);
        asm volatile("s_waitcnt vmcnt(2)" ::: "memory");
        __builtin_amdgcn_s_barrier();

        READ_A_AT(smem_c + 65536 + armul, 0); READ_B_AT(smem_c + 65536 + brmul, 0, bl);
        STAGE_A(1, t2c, 0);
        SYNC_PRE(); MFMA16(0, 0, bl); __builtin_amdgcn_s_setprio(0);
        __builtin_amdgcn_s_barrier();

        READ_B_AT(smem_c + 65536 + brmul, 1, bh);
        STAGE_B(0, t2c, 0);
        SYNC_PRE(); MFMA16(0, 1, bh); __builtin_amdgcn_s_setprio(0);
        __builtin_amdgcn_s_barrier();

        READ_A_AT(smem_c + 65536 + armul, 1);
        STAGE_B(1, t2c, 0);
        SYNC_PRE(); MFMA16(1, 0, bl); __builtin_amdgcn_s_setprio(0);
        __builtin_amdgcn_s_barrier();

        STAGE_A(0, t3c, 1);
        SYNC_PRE(); MFMA16(1, 1, bh); __builtin_amdgcn_s_setprio(0);
        asm volatile("s_waitcnt vmcnt(2)" ::: "memory");
        __builtin_amdgcn_s_barrier();
    }
    asm volatile("s_waitcnt vmcnt(0)" ::: "memory");
#undef STAGE_A
#undef STAGE_B

    const int hi2 = (lane >> 4);
#pragma unroll
    for (int mi = 0; mi < 8; ++mi) {
#pragma unroll
        for (int ni = 0; ni < 4; ++ni) {
            int gcol = bn * 256 + wn * 64 + ni * 16 + l15;
            float bvv = bias[gcol];
            int grow0 = bm * 256 + wm * 128 + mi * 16 + hi2 * 4;
            fx4 v = acc[mi][ni];
#pragma unroll
            for (int j = 0; j < 4; ++j) {
                float x = fmaxf(v[j] + bvv, 0.f);
                Hout[(size_t)(grow0 + j) * N + gcol] = f2bf(x);
            }
        }
    }
}

// ---------------- fused tail: L2 (K=512) + L3 (K=256, in-LDS) + 256->1 dot ----
// Per block: 256 rows. Phase 1: h2 = ReLU(h1 @ W2T + b2) kept in LDS (swizzled
// A-tile layout, 4 x 32KB chunks). Phase 2: h3 = ReLU(h2 @ Wc1T + bc1) fused
// with final dot vs Wc2 -> out fp32. LDS = 128KB (dbuf / h2) + 32KB (B) = 160KB.
__global__ __launch_bounds__(512, 2) void gemm_tail(
    const unsigned short* __restrict__ h1,    // [M x 512] bf16
    const unsigned short* __restrict__ W2T,   // [256 x 512] bf16
    const float* __restrict__ bias2,          // [256]
    const unsigned short* __restrict__ Wc1T,  // [256 x 256] bf16
    const float* __restrict__ bc1,            // [256]
    const float* __restrict__ Wc2,            // [256]
    const float* __restrict__ bc2,            // [1]
    float* __restrict__ outF) {
    __shared__ alignas(16) char smem_c[163840];
    constexpr int K = 512, KT = K / 64;

    const int t = threadIdx.x;
    const int w = t >> 6, lane = t & 63;
    const int wm = w >> 2, wn = w & 3;
    const int bm = blockIdx.x;

    const int l3 = lane >> 3, l7 = lane & 7, l15 = lane & 15;
    const int scs = (l7 ^ l3) << 4;

    const char* Abc = (const char*)h1;
    const char* WTc = (const char*)W2T;
    const char* Wc1c = (const char*)Wc1T;

    uint32_t boff[2][2], aoff[2][2], c2off[4];
#pragma unroll
    for (int h = 0; h < 2; ++h)
#pragma unroll
        for (int r = 0; r < 2; ++r) {
            int srow = h * 128 + w * 8 + l3 + r * 64;
            boff[h][r] = (uint32_t)srow * (uint32_t)(K * 2) + scs;
            aoff[h][r] = (uint32_t)(bm * 256 + srow) * (uint32_t)(K * 2) + scs;
        }
#pragma unroll
    for (int r = 0; r < 4; ++r) {
        int srow = w * 8 + l3 + r * 64;
        c2off[r] = (uint32_t)srow * 512u + scs;  // Wc1T row stride = 256*2
    }

#define TSTAGE_A(hh, tsrc, pb) do { \
    char* d_ = smem_c + (pb) * 65536 + (hh) * 16384 + (w << 10); \
    GLL(Abc + aoff[hh][0] + (tsrc) * 128, d_); \
    GLL(Abc + aoff[hh][1] + (tsrc) * 128, d_ + 8192); \
} while (0)

#define TSTAGE_B(hh, tsrc, pb) do { \
    char* d_ = smem_c + (pb) * 65536 + 32768 + (hh) * 16384 + (w << 10); \
    GLL(WTc + boff[hh][0] + (tsrc) * 128, d_); \
    GLL(WTc + boff[hh][1] + (tsrc) * 128, d_ + 8192); \
} while (0)

    const int armul = wm * 16384 + l15 * 128;
    const int brmul = 32768 + wn * 8192 + l15 * 128;
    const int hi = (lane >> 4) << 4, xl = l7 << 4;
    const int c0 = hi ^ xl, c1 = (64 + hi) ^ xl;

    fx4 acc[8][4];
#pragma unroll
    for (int i = 0; i < 8; ++i)
#pragma unroll
        for (int j = 0; j < 4; ++j) acc[i][j] = {0.f, 0.f, 0.f, 0.f};

    TSTAGE_A(0, 0, 0); TSTAGE_A(1, 0, 0); TSTAGE_B(0, 0, 0); TSTAGE_B(1, 0, 0);
    TSTAGE_A(0, 1, 1);
    asm volatile("s_waitcnt vmcnt(2)" ::: "memory");
    __builtin_amdgcn_s_barrier();

    s16x8 a[8], bl[4], bh[4];
    for (int tt = 0; tt < KT; tt += 2) {
        const int t1 = tt + 1;
        const int t2c = (tt + 2 < KT) ? tt + 2 : KT - 1;
        const int t3c = (tt + 3 < KT) ? tt + 3 : KT - 1;

        READ_A_AT(smem_c + armul, 0); READ_B_AT(smem_c + brmul, 0, bl);
        TSTAGE_A(1, t1, 1);
        SYNC_PRE(); MFMA16(0, 0, bl); __builtin_amdgcn_s_setprio(0);
        __builtin_amdgcn_s_barrier();

        READ_B_AT(smem_c + brmul, 1, bh);
        TSTAGE_B(0, t1, 1);
        SYNC_PRE(); MFMA16(0, 1, bh); __builtin_amdgcn_s_setprio(0);
        __builtin_amdgcn_s_barrier();

        READ_A_AT(smem_c + armul, 1);
        TSTAGE_B(1, t1, 1);
        SYNC_PRE(); MFMA16(1, 0, bl); __builtin_amdgcn_s_setprio(0);
        __builtin_amdgcn_s_barrier();

        TSTAGE_A(0, t2c, 0);
        SYNC_PRE(); MFMA16(1, 1, bh); __builtin_amdgcn_s_setprio(0);
        asm volatile("s_waitcnt vmcnt(2)" ::: "memory");
        __builtin_amdgcn_s_barrier();

        READ_A_AT(smem_c + 65536 + armul, 0); READ_B_AT(smem_c + 65536 + brmul, 0, bl);
        TSTAGE_A(1, t2c, 0);
        SYNC_PRE(); MFMA16(0, 0, bl); __builtin_amdgcn_s_setprio(0);
        __builtin_amdgcn_s_barrier();

        READ_B_AT(smem_c + 65536 + brmul, 1, bh);
        TSTAGE_B(0, t2c, 0);
        SYNC_PRE(); MFMA16(0, 1, bh); __builtin_amdgcn_s_setprio(0);
        __builtin_amdgcn_s_barrier();

        READ_A_AT(smem_c + 65536 + armul, 1);
        TSTAGE_B(1, t2c, 0);
        SYNC_PRE(); MFMA16(1, 0, bl); __builtin_amdgcn_s_setprio(0);
        __builtin_amdgcn_s_barrier();

        TSTAGE_A(0, t3c, 1);
        SYNC_PRE(); MFMA16(1, 1, bh); __builtin_amdgcn_s_setprio(0);
        asm volatile("s_waitcnt vmcnt(2)" ::: "memory");
        __builtin_amdgcn_s_barrier();
    }
    asm volatile("s_waitcnt vmcnt(0)" ::: "memory");
#undef TSTAGE_A
#undef TSTAGE_B

    // ---- phase 1 -> 2: h2 = ReLU(acc + b2) as bf16 into LDS (A-tile layout) ----
    __syncthreads();
    const int hi2 = (lane >> 4);
    {
        float b2v[4];
#pragma unroll
        for (int ni = 0; ni < 4; ++ni) b2v[ni] = bias2[wn * 64 + ni * 16 + l15];
#pragma unroll
        for (int mi = 0; mi < 8; ++mi) {
#pragma unroll
            for (int ni = 0; ni < 4; ++ni) {
                int kin2 = (ni * 16 + l15) * 2;  // byte col within chunk wn
                fx4 v = acc[mi][ni];
#pragma unroll
                for (int j = 0; j < 4; ++j) {
                    int row = wm * 128 + mi * 16 + hi2 * 4 + j;
                    int byte = wn * 32768 + row * 128 + (kin2 ^ ((row & 7) << 4));
                    *(unsigned short*)(smem_c + byte) =
                        f2bf(fmaxf(v[j] + b2v[ni], 0.f));
                }
            }
        }
    }
#pragma unroll
    for (int i = 0; i < 8; ++i)
#pragma unroll
        for (int j = 0; j < 4; ++j) acc[i][j] = {0.f, 0.f, 0.f, 0.f};
    __syncthreads();

    // ---- phase 2: acc = h2 @ Wc1T, B single-buffered at 131072 ----
    const int brmul2 = 131072 + wn * 8192 + l15 * 128;
    for (int kt = 0; kt < 4; ++kt) {
#pragma unroll
        for (int r = 0; r < 4; ++r)
            GLL(Wc1c + c2off[r] + kt * 128, smem_c + 131072 + r * 8192 + (w << 10));
        asm volatile("s_waitcnt vmcnt(0)" ::: "memory");
        __builtin_amdgcn_s_barrier();

        const char* Abase2 = smem_c + kt * 32768 + armul;
        READ_A_AT(Abase2, 0);
        READ_B_AT(smem_c + brmul2 - 131072 + 131072, 0, bl);  // = smem_c+brmul2
        READ_B_AT(smem_c + brmul2, 1, bh);
        asm volatile("s_waitcnt lgkmcnt(0)" ::: "memory");
        __builtin_amdgcn_sched_barrier(0);
        MFMA16(0, 0, bl); MFMA16(0, 1, bh);
        READ_A_AT(Abase2, 1);
        asm volatile("s_waitcnt lgkmcnt(0)" ::: "memory");
        __builtin_amdgcn_sched_barrier(0);
        MFMA16(1, 0, bl); MFMA16(1, 1, bh);
        __builtin_amdgcn_s_barrier();
    }

    // ---- fused epilogue: out[row] = sum_c relu(acc+bc1)*Wc2 + bc2 ----
    float* part = (float*)(smem_c + 131072);
    float bv[4], wv[4];
#pragma unroll
    for (int ni = 0; ni < 4; ++ni) {
        int gcol = wn * 64 + ni * 16 + l15;
        bv[ni] = bc1[gcol];
        wv[ni] = Wc2[gcol];
    }
#pragma unroll
    for (int mi = 0; mi < 8; ++mi) {
#pragma unroll
        for (int j = 0; j < 4; ++j) {
            float s = 0.f;
#pragma unroll
            for (int ni = 0; ni < 4; ++ni)
                s += fmaxf(acc[mi][ni][j] + bv[ni], 0.f) * wv[ni];
            s += __shfl_xor(s, 1); s += __shfl_xor(s, 2);
            s += __shfl_xor(s, 4); s += __shfl_xor(s, 8);
            if (l15 == 0) {
                int row = wm * 128 + mi * 16 + hi2 * 4 + j;
                part[row * 4 + wn] = s;
            }
        }
    }
    __syncthreads();
    if (t < 256) {
        float o2 = part[t * 4] + part[t * 4 + 1] + part[t * 4 + 2] + part[t * 4 + 3] + bc2[0];
        outF[bm * 256 + t] = o2;
    }
}

// ---------------- launch ----------------
extern "C" void kernel_launch(void* const* d_in, const int* in_sizes, int n_in,
                              void* d_out, int out_size, void* d_ws, size_t ws_size,
                              hipStream_t stream) {
    const float* local_emb  = (const float*)d_in[0];
    const float* global_emb = (const float*)d_in[1];
    const int* unary_idx    = (const int*)d_in[2];
    const int* binary_idx   = (const int*)d_in[3];
    const float* Wb1 = (const float*)d_in[4];
    const float* bb1 = (const float*)d_in[5];
    const float* Wb2 = (const float*)d_in[6];
    const float* bb2 = (const float*)d_in[7];
    const float* Wt1 = (const float*)d_in[8];
    const float* bt1 = (const float*)d_in[9];
    const float* Wt2 = (const float*)d_in[10];
    const float* bt2 = (const float*)d_in[11];
    const float* Wc1 = (const float*)d_in[12];
    const float* bc1 = (const float*)d_in[13];
    const float* Wc2 = (const float*)d_in[14];
    const float* bc2 = (const float*)d_in[15];
    float* out = (float*)d_out;

    constexpr int Hd = 256, U = 65536, B = 65536;
    const int NN = in_sizes[0] / Hd;

    char* ws = (char*)d_ws;
    size_t off = 0;
    auto alloc = [&](size_t bytes) {
        char* p = ws + off;
        off += (bytes + 255) & ~(size_t)255;
        return p;
    };
    unsigned short* emb_bf = (unsigned short*)alloc((size_t)NN * Hd * 2);
    unsigned short* W1uT   = (unsigned short*)alloc(512 * 512 * 2);
    unsigned short* W2uT   = (unsigned short*)alloc(256 * 512 * 2);
    unsigned short* W1bT   = (unsigned short*)alloc(512 * 768 * 2);
    unsigned short* W2bT   = (unsigned short*)alloc(256 * 512 * 2);
    unsigned short* Wc1T   = (unsigned short*)alloc(256 * 256 * 2);
    float* bu              = (float*)alloc(512 * 4);
    float* bbn             = (float*)alloc(512 * 4);
    unsigned short* h1     = (unsigned short*)alloc((size_t)U * 512 * 2);

    int n4 = NN * Hd / 4;
    conv4<<<(n4 + 255) / 256, 256, 0, stream>>>(local_emb, emb_bf, n4);
    convT<<<(512 * 512 + 255) / 256, 256, 0, stream>>>(Wb1, W1uT, 512, 512);
    convT<<<(256 * 512 + 255) / 256, 256, 0, stream>>>(Wb2, W2uT, 512, 256);
    convT<<<(512 * 768 + 255) / 256, 256, 0, stream>>>(Wt1, W1bT, 768, 512);
    convT<<<(256 * 512 + 255) / 256, 256, 0, stream>>>(Wt2, W2bT, 512, 256);
    convT<<<(256 * 256 + 255) / 256, 256, 0, stream>>>(Wc1, Wc1T, 256, 256);
    foldbias<<<512, 64, 0, stream>>>(global_emb, Wb1, bb1, bu, 512, 512);
    foldbias<<<512, 64, 0, stream>>>(global_emb, Wt1, bt1, bbn, 768, 512);

    dim3 blk(512);
    // unary branch (K = 2H = 512 after bias-fold)
    gemm256<1, 512, 2><<<dim3(512), blk, 0, stream>>>(
        emb_bf, unary_idx, W1uT, bu, h1, 512, 2);
    gemm_tail<<<dim3(256), blk, 0, stream>>>(h1, W2uT, bb2, Wc1T, bc1, Wc2, bc2, out);
    // binary branch (K = 3H = 768 after bias-fold; reuses h1)
    gemm256<2, 768, 3><<<dim3(512), blk, 0, stream>>>(
        emb_bf, binary_idx, W1bT, bbn, h1, 512, 2);
    gemm_tail<<<dim3(256), blk, 0, stream>>>(h1, W2bT, bt2, Wc1T, bc1, Wc2, bc2, out + U);

    (void)n_in; (void)out_size; (void)ws_size;
}

// Round 6
// 218.289 us; speedup vs baseline: 1.3573x; 1.0660x over previous
//
#include <hip/hip_runtime.h>
#include <cstdint>
#include <cstddef>

typedef __attribute__((ext_vector_type(8))) short s16x8;   // 8 x bf16 bits
typedef __attribute__((ext_vector_type(4))) float fx4;     // MFMA accumulator

#define AS1 __attribute__((address_space(1)))
#define AS3 __attribute__((address_space(3)))

__device__ __forceinline__ unsigned short f2bf(float f) {
    union { float f; unsigned u; } c; c.f = f;
    unsigned lsb = (c.u >> 16) & 1u;
    unsigned r = c.u + 0x7fffu + lsb;
    return (unsigned short)(r >> 16);
}

// ---------------- merged prep kernel ----------------
// sections by blockIdx.x: [0,NB1) emb fp32->bf16 | [NB1,NB1+3840) convT x5 |
// [NB1+3840, NB1+4096) bias-fold (4 waves/block, 1 col/wave).
__device__ __forceinline__ void ctj(const float* __restrict__ W,
                                    unsigned short* __restrict__ WT,
                                    int K, int N, int brel, int tid) {
    int i = brel * 256 + tid;
    int n = i / K, k = i - n * K;
    WT[i] = f2bf(W[(size_t)k * N + n]);
}

__global__ __launch_bounds__(256) void prep(
    const float* __restrict__ emb, unsigned short* __restrict__ emb_bf,
    int n4, int NB1,
    const float* __restrict__ Wb1, unsigned short* __restrict__ W1uT,
    const float* __restrict__ Wb2, unsigned short* __restrict__ W2uT,
    const float* __restrict__ Wt1, unsigned short* __restrict__ W1bT,
    const float* __restrict__ Wt2, unsigned short* __restrict__ W2bT,
    const float* __restrict__ Wc1, unsigned short* __restrict__ Wc1T,
    const float* __restrict__ g, const float* __restrict__ bb1,
    const float* __restrict__ bt1,
    float* __restrict__ bu, float* __restrict__ bbn) {
    int bid = blockIdx.x, tid = threadIdx.x;
    if (bid < NB1) {
        int i = bid * 256 + tid;
        if (i < n4) {
            float4 v = reinterpret_cast<const float4*>(emb)[i];
            ushort4 o;
            o.x = f2bf(v.x); o.y = f2bf(v.y); o.z = f2bf(v.z); o.w = f2bf(v.w);
            reinterpret_cast<ushort4*>(emb_bf)[i] = o;
        }
        return;
    }
    int b2 = bid - NB1;
    if (b2 < 3840) {
        if (b2 < 1024)      ctj(Wb1, W1uT, 512, 512, b2, tid);
        else if (b2 < 1536) ctj(Wb2, W2uT, 512, 256, b2 - 1024, tid);
        else if (b2 < 3072) ctj(Wt1, W1bT, 768, 512, b2 - 1536, tid);
        else if (b2 < 3584) ctj(Wt2, W2bT, 512, 256, b2 - 3072, tid);
        else                ctj(Wc1, Wc1T, 256, 256, b2 - 3584, tid);
        return;
    }
    int b3 = b2 - 3840;                 // 0..255
    int wv = tid >> 6, lane = tid & 63;
    int col = b3 * 4 + wv;              // 0..1023
    const float* W  = (col < 512) ? Wb1 : Wt1;
    const float* bs = (col < 512) ? bb1 : bt1;
    float* dst      = (col < 512) ? bu  : bbn;
    int K0          = (col < 512) ? 512 : 768;
    int n = col & 511;
    float s = 0.f;
#pragma unroll
    for (int j = 0; j < 4; ++j) {
        int k = lane + j * 64;
        s += g[k] * W[(size_t)(K0 + k) * 512 + n];
    }
#pragma unroll
    for (int off = 32; off > 0; off >>= 1) s += __shfl_xor(s, off, 64);
    if (lane == 0) dst[n] = bs[n] + s;
}

// ================= shared GEMM building-block macros =================
// BM=256, BN=256, BK=64; 8 waves = 2(M) x 4(N), wave tile 128x64.
// LDS buf layout (64KB/buf): A 32KB (2 halves of 128 rows x 128B) | B 32KB.
// Swizzle: element k of row r stored at byte (2k) ^ ((r&7)<<4) within row.

#define GLL(src, dst) __builtin_amdgcn_global_load_lds((AS1 void*)(src), (AS3 void*)(dst), 16, 0, 0)

#define MFMA16(mh, nh, BARR) do { \
    _Pragma("unroll") for (int ks_ = 0; ks_ < 2; ++ks_) \
    _Pragma("unroll") for (int r_ = 0; r_ < 4; ++r_) \
    _Pragma("unroll") for (int c_ = 0; c_ < 2; ++c_) \
        acc[(mh) * 4 + r_][(nh) * 2 + c_] = __builtin_amdgcn_mfma_f32_16x16x32_bf16( \
            a[r_ * 2 + ks_], BARR[c_ * 2 + ks_], acc[(mh) * 4 + r_][(nh) * 2 + c_], 0, 0, 0); \
} while (0)

#define SYNC_PRE() do { \
    __builtin_amdgcn_s_barrier(); \
    asm volatile("s_waitcnt lgkmcnt(0)" ::: "memory"); \
    __builtin_amdgcn_sched_barrier(0); \
    __builtin_amdgcn_s_setprio(1); \
} while (0)

#define READ_A_AT(basep, mh) do { \
    const char* base_ = (basep); \
    _Pragma("unroll") for (int r_ = 0; r_ < 4; ++r_) { \
        a[r_ * 2 + 0] = *(const s16x8*)(base_ + ((mh) * 4 + r_) * 2048 + c0); \
        a[r_ * 2 + 1] = *(const s16x8*)(base_ + ((mh) * 4 + r_) * 2048 + c1); \
    } \
} while (0)

#define READ_B_AT(basep, nh, BARR) do { \
    const char* base_ = (basep); \
    _Pragma("unroll") for (int c_ = 0; c_ < 2; ++c_) { \
        BARR[c_ * 2 + 0] = *(const s16x8*)(base_ + ((nh) * 2 + c_) * 2048 + c0); \
        BARR[c_ * 2 + 1] = *(const s16x8*)(base_ + ((nh) * 2 + c_) * 2048 + c1); \
    } \
} while (0)

// ---------------- layer-1: 8-phase 256x256 gathered GEMM ----------------
template <int MODE, int K, int NODES>
__global__ __launch_bounds__(512, 2) void gemm256(
    const unsigned short* __restrict__ Abase,
    const int* __restrict__ idx,
    const unsigned short* __restrict__ WT,
    const float* __restrict__ bias,
    unsigned short* __restrict__ Hout,
    int N, int nbn) {
    __shared__ alignas(16) char smem_c[131072];
    constexpr int KT = K / 64;

    const int t = threadIdx.x;
    const int w = t >> 6, lane = t & 63;
    const int wm = w >> 2, wn = w & 3;

    const int nwg = gridDim.x, o = blockIdx.x, q = nwg >> 3;
    const int widx = (o & 7) * q + (o >> 3);
    const int bn = widx % nbn, bm = widx / nbn;

    const int l3 = lane >> 3, l7 = lane & 7, l15 = lane & 15;
    const int scs = (l7 ^ l3) << 4;

    const char* Abc = (const char*)Abase;
    const char* WTc = (const char*)WT;

    uint32_t boff[2][2];
    uint32_t aoff[2][2][NODES];
#pragma unroll
    for (int h = 0; h < 2; ++h)
#pragma unroll
        for (int r = 0; r < 2; ++r) {
            int srow = h * 128 + w * 8 + l3 + r * 64;
            boff[h][r] = (uint32_t)(bn * 256 + srow) * (uint32_t)(K * 2) + scs;
            int gm = bm * 256 + srow;
            if constexpr (MODE == 0) {
                aoff[h][r][0] = (uint32_t)gm * (uint32_t)(K * 2) + scs;
            } else {
#pragma unroll
                for (int s = 0; s < NODES; ++s)
                    aoff[h][r][s] = (uint32_t)idx[(size_t)gm * NODES + s] * 512u + scs;
            }
        }

#define STAGE_A(hh, tsrc, pb) do { \
    char* d_ = smem_c + (pb) * 65536 + (hh) * 16384 + (w << 10); \
    if constexpr (MODE == 0) { \
        GLL(Abc + aoff[hh][0][0] + (tsrc) * 128, d_); \
        GLL(Abc + aoff[hh][1][0] + (tsrc) * 128, d_ + 8192); \
    } else { \
        int seg_ = (tsrc) >> 2, k4_ = ((tsrc) & 3) << 7; \
        uint32_t v0_ = aoff[hh][0][0], v1_ = aoff[hh][1][0]; \
        if constexpr (NODES >= 2) { if (seg_ >= 1) { v0_ = aoff[hh][0][1]; v1_ = aoff[hh][1][1]; } } \
        if constexpr (NODES >= 3) { if (seg_ >= 2) { v0_ = aoff[hh][0][2]; v1_ = aoff[hh][1][2]; } } \
        GLL(Abc + v0_ + k4_, d_); GLL(Abc + v1_ + k4_, d_ + 8192); \
    } \
} while (0)

#define STAGE_B(hh, tsrc, pb) do { \
    char* d_ = smem_c + (pb) * 65536 + 32768 + (hh) * 16384 + (w << 10); \
    GLL(WTc + boff[hh][0] + (tsrc) * 128, d_); \
    GLL(WTc + boff[hh][1] + (tsrc) * 128, d_ + 8192); \
} while (0)

    const int armul = wm * 16384 + l15 * 128;
    const int brmul = 32768 + wn * 8192 + l15 * 128;
    const int hi = (lane >> 4) << 4, xl = l7 << 4;
    const int c0 = hi ^ xl, c1 = (64 + hi) ^ xl;

    fx4 acc[8][4];
#pragma unroll
    for (int i = 0; i < 8; ++i)
#pragma unroll
        for (int j = 0; j < 4; ++j) acc[i][j] = {0.f, 0.f, 0.f, 0.f};

    STAGE_A(0, 0, 0); STAGE_A(1, 0, 0); STAGE_B(0, 0, 0); STAGE_B(1, 0, 0);
    STAGE_A(0, 1, 1);
    asm volatile("s_waitcnt vmcnt(2)" ::: "memory");
    __builtin_amdgcn_s_barrier();

    s16x8 a[8], bl[4], bh[4];
    for (int tt = 0; tt < KT; tt += 2) {
        const int t1 = tt + 1;
        const int t2c = (tt + 2 < KT) ? tt + 2 : KT - 1;
        const int t3c = (tt + 3 < KT) ? tt + 3 : KT - 1;

        READ_A_AT(smem_c + armul, 0); READ_B_AT(smem_c + brmul, 0, bl);
        STAGE_A(1, t1, 1);
        SYNC_PRE(); MFMA16(0, 0, bl); __builtin_amdgcn_s_setprio(0);
        __builtin_amdgcn_s_barrier();

        READ_B_AT(smem_c + brmul, 1, bh);
        STAGE_B(0, t1, 1);
        SYNC_PRE(); MFMA16(0, 1, bh); __builtin_amdgcn_s_setprio(0);
        __builtin_amdgcn_s_barrier();

        READ_A_AT(smem_c + armul, 1);
        STAGE_B(1, t1, 1);
        SYNC_PRE(); MFMA16(1, 0, bl); __builtin_amdgcn_s_setprio(0);
        __builtin_amdgcn_s_barrier();

        STAGE_A(0, t2c, 0);
        SYNC_PRE(); MFMA16(1, 1, bh); __builtin_amdgcn_s_setprio(0);
        asm volatile("s_waitcnt vmcnt(2)" ::: "memory");
        __builtin_amdgcn_s_barrier();

        READ_A_AT(smem_c + 65536 + armul, 0); READ_B_AT(smem_c + 65536 + brmul, 0, bl);
        STAGE_A(1, t2c, 0);
        SYNC_PRE(); MFMA16(0, 0, bl); __builtin_amdgcn_s_setprio(0);
        __builtin_amdgcn_s_barrier();

        READ_B_AT(smem_c + 65536 + brmul, 1, bh);
        STAGE_B(0, t2c, 0);
        SYNC_PRE(); MFMA16(0, 1, bh); __builtin_amdgcn_s_setprio(0);
        __builtin_amdgcn_s_barrier();

        READ_A_AT(smem_c + 65536 + armul, 1);
        STAGE_B(1, t2c, 0);
        SYNC_PRE(); MFMA16(1, 0, bl); __builtin_amdgcn_s_setprio(0);
        __builtin_amdgcn_s_barrier();

        STAGE_A(0, t3c, 1);
        SYNC_PRE(); MFMA16(1, 1, bh); __builtin_amdgcn_s_setprio(0);
        asm volatile("s_waitcnt vmcnt(2)" ::: "memory");
        __builtin_amdgcn_s_barrier();
    }
    asm volatile("s_waitcnt vmcnt(0)" ::: "memory");
#undef STAGE_A
#undef STAGE_B

    const int hi2 = (lane >> 4);
#pragma unroll
    for (int mi = 0; mi < 8; ++mi) {
#pragma unroll
        for (int ni = 0; ni < 4; ++ni) {
            int gcol = bn * 256 + wn * 64 + ni * 16 + l15;
            float bvv = bias[gcol];
            int grow0 = bm * 256 + wm * 128 + mi * 16 + hi2 * 4;
            fx4 v = acc[mi][ni];
#pragma unroll
            for (int j = 0; j < 4; ++j) {
                float x = fmaxf(v[j] + bvv, 0.f);
                Hout[(size_t)(grow0 + j) * N + gcol] = f2bf(x);
            }
        }
    }
}

// ---------------- fused tail (both branches): L2 + L3 + 256->1 dot ----------
// grid 512: branch = bid&1, bm = bid>>1.
// Phase 1: h2 = ReLU(h1 @ W2T + b2) -> LDS [0,128KB) as 4 chunks (wn) of
//   256 rows x 128B, XOR-swizzled like A-tiles.
// Phase 2: BK=32 pipelined GEMM vs Wc1T. B chunk = 16KB at [128KB,160KB),
//   double-buffered, counted vmcnt(2). Chunk layout: 128 lines x 128B,
//   line l = rows {2l,2l+1}; 16B-unit ulog = (r&1)*4+g stored at u = ulog^(l&7).
//   Bank check (read, 16 lanes same g, rows r..r+15): addr/4%32 =
//   ((r&1)*16+4g)^(4l), l=r>>1 in 0..7 -> 16 distinct banks, conflict-free.
__global__ __launch_bounds__(512, 2) void gemm_tail(
    const unsigned short* __restrict__ h1u,
    const unsigned short* __restrict__ h1b,
    const unsigned short* __restrict__ W2uT,
    const unsigned short* __restrict__ W2bT,
    const float* __restrict__ bb2,
    const float* __restrict__ bt2,
    const unsigned short* __restrict__ Wc1T,
    const float* __restrict__ bc1,
    const float* __restrict__ Wc2,
    const float* __restrict__ bc2,
    float* __restrict__ outF, int U) {
    __shared__ alignas(16) char smem_c[163840];
    constexpr int K = 512, KT = K / 64;

    const int t = threadIdx.x;
    const int w = t >> 6, lane = t & 63;
    const int wm = w >> 2, wn = w & 3;
    const int br = blockIdx.x & 1;
    const int bm = blockIdx.x >> 1;

    const unsigned short* h1  = br ? h1b : h1u;
    const unsigned short* W2T = br ? W2bT : W2uT;
    const float* bias2        = br ? bt2 : bb2;
    float* outp               = outF + br * U;

    const int l3 = lane >> 3, l7 = lane & 7, l15 = lane & 15;
    const int scs = (l7 ^ l3) << 4;

    const char* Abc = (const char*)h1;
    const char* WTc = (const char*)W2T;
    const char* Wc1c = (const char*)Wc1T;

    uint32_t boff[2][2], aoff[2][2];
#pragma unroll
    for (int h = 0; h < 2; ++h)
#pragma unroll
        for (int r = 0; r < 2; ++r) {
            int srow = h * 128 + w * 8 + l3 + r * 64;
            boff[h][r] = (uint32_t)srow * (uint32_t)(K * 2) + scs;
            aoff[h][r] = (uint32_t)(bm * 256 + srow) * (uint32_t)(K * 2) + scs;
        }

    // phase-2 stage geometry: pass p covers linear o = p*8192 + t*16
    uint32_t p2src[2], p2dst[2];
#pragma unroll
    for (int p = 0; p < 2; ++p) {
        int o = p * 8192 + t * 16;
        int l = o >> 7, u = (o >> 4) & 7;
        int ulog = u ^ (l & 7);
        int r = 2 * l + (ulog >> 2), gg = ulog & 3;
        p2src[p] = (uint32_t)r * 512u + (uint32_t)gg * 16u;  // + kt*64
        p2dst[p] = (uint32_t)o;
    }

#define TSTAGE_A(hh, tsrc, pb) do { \
    char* d_ = smem_c + (pb) * 65536 + (hh) * 16384 + (w << 10); \
    GLL(Abc + aoff[hh][0] + (tsrc) * 128, d_); \
    GLL(Abc + aoff[hh][1] + (tsrc) * 128, d_ + 8192); \
} while (0)

#define TSTAGE_B(hh, tsrc, pb) do { \
    char* d_ = smem_c + (pb) * 65536 + 32768 + (hh) * 16384 + (w << 10); \
    GLL(WTc + boff[hh][0] + (tsrc) * 128, d_); \
    GLL(WTc + boff[hh][1] + (tsrc) * 128, d_ + 8192); \
} while (0)

#define STAGE2(kt, buf) do { \
    char* d_ = smem_c + 131072 + (buf) * 16384; \
    GLL(Wc1c + p2src[0] + (kt) * 64, d_ + p2dst[0]); \
    GLL(Wc1c + p2src[1] + (kt) * 64, d_ + p2dst[1]); \
} while (0)

    const int armul = wm * 16384 + l15 * 128;
    const int brmul = 32768 + wn * 8192 + l15 * 128;
    const int hi = (lane >> 4) << 4, xl = l7 << 4;
    const int c0 = hi ^ xl, c1 = (64 + hi) ^ xl;

    fx4 acc[8][4];
#pragma unroll
    for (int i = 0; i < 8; ++i)
#pragma unroll
        for (int j = 0; j < 4; ++j) acc[i][j] = {0.f, 0.f, 0.f, 0.f};

    TSTAGE_A(0, 0, 0); TSTAGE_A(1, 0, 0); TSTAGE_B(0, 0, 0); TSTAGE_B(1, 0, 0);
    TSTAGE_A(0, 1, 1);
    asm volatile("s_waitcnt vmcnt(2)" ::: "memory");
    __builtin_amdgcn_s_barrier();

    s16x8 a[8], bl[4], bh[4];
    for (int tt = 0; tt < KT; tt += 2) {
        const int t1 = tt + 1;
        const int t2c = (tt + 2 < KT) ? tt + 2 : KT - 1;
        const int t3c = (tt + 3 < KT) ? tt + 3 : KT - 1;

        READ_A_AT(smem_c + armul, 0); READ_B_AT(smem_c + brmul, 0, bl);
        TSTAGE_A(1, t1, 1);
        SYNC_PRE(); MFMA16(0, 0, bl); __builtin_amdgcn_s_setprio(0);
        __builtin_amdgcn_s_barrier();

        READ_B_AT(smem_c + brmul, 1, bh);
        TSTAGE_B(0, t1, 1);
        SYNC_PRE(); MFMA16(0, 1, bh); __builtin_amdgcn_s_setprio(0);
        __builtin_amdgcn_s_barrier();

        READ_A_AT(smem_c + armul, 1);
        TSTAGE_B(1, t1, 1);
        SYNC_PRE(); MFMA16(1, 0, bl); __builtin_amdgcn_s_setprio(0);
        __builtin_amdgcn_s_barrier();

        TSTAGE_A(0, t2c, 0);
        SYNC_PRE(); MFMA16(1, 1, bh); __builtin_amdgcn_s_setprio(0);
        asm volatile("s_waitcnt vmcnt(2)" ::: "memory");
        __builtin_amdgcn_s_barrier();

        READ_A_AT(smem_c + 65536 + armul, 0); READ_B_AT(smem_c + 65536 + brmul, 0, bl);
        TSTAGE_A(1, t2c, 0);
        SYNC_PRE(); MFMA16(0, 0, bl); __builtin_amdgcn_s_setprio(0);
        __builtin_amdgcn_s_barrier();

        READ_B_AT(smem_c + 65536 + brmul, 1, bh);
        TSTAGE_B(0, t2c, 0);
        SYNC_PRE(); MFMA16(0, 1, bh); __builtin_amdgcn_s_setprio(0);
        __builtin_amdgcn_s_barrier();

        READ_A_AT(smem_c + 65536 + armul, 1);
        TSTAGE_B(1, t2c, 0);
        SYNC_PRE(); MFMA16(1, 0, bl); __builtin_amdgcn_s_setprio(0);
        __builtin_amdgcn_s_barrier();

        TSTAGE_A(0, t3c, 1);
        SYNC_PRE(); MFMA16(1, 1, bh); __builtin_amdgcn_s_setprio(0);
        asm volatile("s_waitcnt vmcnt(2)" ::: "memory");
        __builtin_amdgcn_s_barrier();
    }
    asm volatile("s_waitcnt vmcnt(0)" ::: "memory");
#undef TSTAGE_A
#undef TSTAGE_B

    // issue first two phase-2 B chunks now; latency hides under h2 writes
    STAGE2(0, 0); STAGE2(1, 1);

    // ---- h2 = ReLU(acc + b2) as bf16 into LDS (A-tile layout) ----
    __syncthreads();
    const int hi2 = (lane >> 4);
    {
        float b2v[4];
#pragma unroll
        for (int ni = 0; ni < 4; ++ni) b2v[ni] = bias2[wn * 64 + ni * 16 + l15];
#pragma unroll
        for (int mi = 0; mi < 8; ++mi) {
#pragma unroll
            for (int ni = 0; ni < 4; ++ni) {
                int kin2 = (ni * 16 + l15) * 2;
                fx4 v = acc[mi][ni];
#pragma unroll
                for (int j = 0; j < 4; ++j) {
                    int row = wm * 128 + mi * 16 + hi2 * 4 + j;
                    int byte = wn * 32768 + row * 128 + (kin2 ^ ((row & 7) << 4));
                    *(unsigned short*)(smem_c + byte) =
                        f2bf(fmaxf(v[j] + b2v[ni], 0.f));
                }
            }
        }
    }
#pragma unroll
    for (int i = 0; i < 8; ++i)
#pragma unroll
        for (int j = 0; j < 4; ++j) acc[i][j] = {0.f, 0.f, 0.f, 0.f};
    __syncthreads();

    // ---- phase 2: 8 chunks of BK=32, dbuf, counted vmcnt ----
    const int g2 = lane >> 4;  // k-group 0..3
    for (int kt = 0; kt < 8; ++kt) {
        if (kt < 7) { asm volatile("s_waitcnt vmcnt(2)" ::: "memory"); }
        else        { asm volatile("s_waitcnt vmcnt(0)" ::: "memory"); }
        __builtin_amdgcn_s_barrier();

        s16x8 a2[8], b2f[4];
        const int kc = kt >> 1, half = kt & 1;
        const int cb = half * 64 + (g2 << 4);
        const char* ab = smem_c + kc * 32768;
#pragma unroll
        for (int m = 0; m < 8; ++m) {
            int row = wm * 128 + m * 16 + l15;
            a2[m] = *(const s16x8*)(ab + row * 128 + (cb ^ ((row & 7) << 4)));
        }
        const char* bb = smem_c + 131072 + (kt & 1) * 16384;
#pragma unroll
        for (int f = 0; f < 4; ++f) {
            int r = wn * 64 + f * 16 + l15;
            int l = r >> 1;
            int u = (((r & 1) << 2) | g2) ^ (l & 7);
            b2f[f] = *(const s16x8*)(bb + l * 128 + u * 16);
        }
        asm volatile("s_waitcnt lgkmcnt(0)" ::: "memory");
        __builtin_amdgcn_sched_barrier(0);
        __builtin_amdgcn_s_barrier();
        if (kt + 2 < 8) STAGE2(kt + 2, kt & 1);
        __builtin_amdgcn_s_setprio(1);
#pragma unroll
        for (int m = 0; m < 8; ++m)
#pragma unroll
            for (int f = 0; f < 4; ++f)
                acc[m][f] = __builtin_amdgcn_mfma_f32_16x16x32_bf16(
                    a2[m], b2f[f], acc[m][f], 0, 0, 0);
        __builtin_amdgcn_s_setprio(0);
    }
#undef STAGE2

    // ---- fused epilogue: out[row] = sum_c relu(acc+bc1)*Wc2 + bc2 ----
    float* part = (float*)(smem_c + 131072);
    float bv[4], wv[4];
#pragma unroll
    for (int ni = 0; ni < 4; ++ni) {
        int gcol = wn * 64 + ni * 16 + l15;
        bv[ni] = bc1[gcol];
        wv[ni] = Wc2[gcol];
    }
#pragma unroll
    for (int mi = 0; mi < 8; ++mi) {
#pragma unroll
        for (int j = 0; j < 4; ++j) {
            float s = 0.f;
#pragma unroll
            for (int ni = 0; ni < 4; ++ni)
                s += fmaxf(acc[mi][ni][j] + bv[ni], 0.f) * wv[ni];
            s += __shfl_xor(s, 1); s += __shfl_xor(s, 2);
            s += __shfl_xor(s, 4); s += __shfl_xor(s, 8);
            if (l15 == 0) {
                int row = wm * 128 + mi * 16 + hi2 * 4 + j;
                part[row * 4 + wn] = s;
            }
        }
    }
    __syncthreads();
    if (t < 256) {
        float o2 = part[t * 4] + part[t * 4 + 1] + part[t * 4 + 2] + part[t * 4 + 3] + bc2[0];
        outp[bm * 256 + t] = o2;
    }
}

// ---------------- launch ----------------
extern "C" void kernel_launch(void* const* d_in, const int* in_sizes, int n_in,
                              void* d_out, int out_size, void* d_ws, size_t ws_size,
                              hipStream_t stream) {
    const float* local_emb  = (const float*)d_in[0];
    const float* global_emb = (const float*)d_in[1];
    const int* unary_idx    = (const int*)d_in[2];
    const int* binary_idx   = (const int*)d_in[3];
    const float* Wb1 = (const float*)d_in[4];
    const float* bb1 = (const float*)d_in[5];
    const float* Wb2 = (const float*)d_in[6];
    const float* bb2 = (const float*)d_in[7];
    const float* Wt1 = (const float*)d_in[8];
    const float* bt1 = (const float*)d_in[9];
    const float* Wt2 = (const float*)d_in[10];
    const float* bt2 = (const float*)d_in[11];
    const float* Wc1 = (const float*)d_in[12];
    const float* bc1 = (const float*)d_in[13];
    const float* Wc2 = (const float*)d_in[14];
    const float* bc2 = (const float*)d_in[15];
    float* out = (float*)d_out;

    constexpr int Hd = 256, U = 65536;
    const int NN = in_sizes[0] / Hd;

    char* ws = (char*)d_ws;
    size_t off = 0;
    auto alloc = [&](size_t bytes) {
        char* p = ws + off;
        off += (bytes + 255) & ~(size_t)255;
        return p;
    };
    unsigned short* emb_bf = (unsigned short*)alloc((size_t)NN * Hd * 2);
    unsigned short* W1uT   = (unsigned short*)alloc(512 * 512 * 2);
    unsigned short* W2uT   = (unsigned short*)alloc(256 * 512 * 2);
    unsigned short* W1bT   = (unsigned short*)alloc(512 * 768 * 2);
    unsigned short* W2bT   = (unsigned short*)alloc(256 * 512 * 2);
    unsigned short* Wc1T   = (unsigned short*)alloc(256 * 256 * 2);
    float* bu              = (float*)alloc(512 * 4);
    float* bbn             = (float*)alloc(512 * 4);
    unsigned short* h1u    = (unsigned short*)alloc((size_t)U * 512 * 2);
    unsigned short* h1b    = (unsigned short*)alloc((size_t)U * 512 * 2);

    int n4 = NN * 64;                 // float4 groups in embedding
    int NB1 = (n4 + 255) / 256;
    prep<<<dim3(NB1 + 3840 + 256), dim3(256), 0, stream>>>(
        local_emb, emb_bf, n4, NB1,
        Wb1, W1uT, Wb2, W2uT, Wt1, W1bT, Wt2, W2bT, Wc1, Wc1T,
        global_emb, bb1, bt1, bu, bbn);

    dim3 blk(512);
    gemm256<1, 512, 2><<<dim3(512), blk, 0, stream>>>(
        emb_bf, unary_idx, W1uT, bu, h1u, 512, 2);
    gemm256<2, 768, 3><<<dim3(512), blk, 0, stream>>>(
        emb_bf, binary_idx, W1bT, bbn, h1b, 512, 2);
    gemm_tail<<<dim3(512), blk, 0, stream>>>(
        h1u, h1b, W2uT, W2bT, bb2, bt2, Wc1T, bc1, Wc2, bc2, out, U);

    (void)n_in; (void)out_size; (void)ws_size;
}